// Round 1
// baseline (972.402 us; speedup 1.0000x reference)
//
#include <hip/hip_runtime.h>

#define BATCH 16
#define NPIX 1024      // 32*32
#define CH 512
#define HEADS 8
#define HD 64
#define GROUPS 32
#define CG 16          // CH/GROUPS
#define QKVW 1536      // 3*512

// ---------------------------------------------------------------------------
// Stage 1: GroupNorm (32 groups over h,w,c/g) + SiLU.  One block = (b, g).
// ---------------------------------------------------------------------------
__global__ __launch_bounds__(256) void gn_silu_kernel(
    const float* __restrict__ x, const float* __restrict__ sc,
    const float* __restrict__ of, float* __restrict__ y) {
  const int b = blockIdx.x >> 5, g = blockIdx.x & 31;
  const size_t base = (size_t)b * NPIX * CH + (size_t)g * CG;
  const int t = threadIdx.x;

  float sum = 0.f, ssq = 0.f;
#pragma unroll
  for (int it = 0; it < 16; ++it) {
    const int e4 = t + 256 * it;           // 4096 float4 units = 16384 floats
    const int p = e4 >> 2, c = (e4 & 3) * 4;
    const float4 v = *reinterpret_cast<const float4*>(x + base + (size_t)p * CH + c);
    sum += v.x + v.y + v.z + v.w;
    ssq += v.x * v.x + v.y * v.y + v.z * v.z + v.w * v.w;
  }
#pragma unroll
  for (int m = 32; m > 0; m >>= 1) {
    sum += __shfl_down(sum, m);
    ssq += __shfl_down(ssq, m);
  }
  __shared__ float rs[4], rq[4], mv[2];
  const int lane = t & 63, wid = t >> 6;
  if (lane == 0) { rs[wid] = sum; rq[wid] = ssq; }
  __syncthreads();
  if (t == 0) {
    const float s = rs[0] + rs[1] + rs[2] + rs[3];
    const float q = rq[0] + rq[1] + rq[2] + rq[3];
    const float mean = s * (1.f / 16384.f);
    const float var = q * (1.f / 16384.f) - mean * mean;
    mv[0] = mean;
    mv[1] = rsqrtf(var + 1e-5f);
  }
  __syncthreads();
  const float mean = mv[0], rstd = mv[1];

#pragma unroll
  for (int it = 0; it < 16; ++it) {
    const int e4 = t + 256 * it;
    const int p = e4 >> 2, c = (e4 & 3) * 4;
    const float4 v = *reinterpret_cast<const float4*>(x + base + (size_t)p * CH + c);
    const float4 s4 = *reinterpret_cast<const float4*>(sc + g * CG + c);
    const float4 o4 = *reinterpret_cast<const float4*>(of + g * CG + c);
    float4 r;
    r.x = (v.x - mean) * rstd * s4.x + o4.x;
    r.y = (v.y - mean) * rstd * s4.y + o4.y;
    r.z = (v.z - mean) * rstd * s4.z + o4.z;
    r.w = (v.w - mean) * rstd * s4.w + o4.w;
    r.x = r.x / (1.f + __expf(-r.x));
    r.y = r.y / (1.f + __expf(-r.y));
    r.z = r.z / (1.f + __expf(-r.z));
    r.w = r.w / (1.f + __expf(-r.w));
    *reinterpret_cast<float4*>(y + base + (size_t)p * CH + c) = r;
  }
}

// ---------------------------------------------------------------------------
// Stages 2 & 4: fp32 GEMM  C[M,N] = A[M,K] @ B[K,N]  (+ bias + residual).
// 128x128 tile, BK=16, 256 threads, 8x8 per thread.
// M, N multiples of 128; K multiple of 16.
// ---------------------------------------------------------------------------
template <bool EPI>
__global__ __launch_bounds__(256) void gemm128_kernel(
    const float* __restrict__ A, const float* __restrict__ Bm,
    float* __restrict__ C, const int M, const int N, const int K,
    const float* __restrict__ bias, const float* __restrict__ resid) {
  __shared__ float As[16][132];   // transposed A tile: As[k][m] (132: 16B-aligned rows)
  __shared__ float Bs[16][128];   // Bs[k][n]
  const int t = threadIdx.x;
  const int nb = N >> 7;
  const int m0 = (blockIdx.x / nb) << 7;
  const int n0 = (blockIdx.x % nb) << 7;
  const int tx = t & 15, ty = t >> 4;

  float acc[8][8] = {};
  const int ar = t >> 2, ac = (t & 3) << 2;   // A: row 0..63 (+64), col 0/4/8/12
  const int br = t >> 5, bc = (t & 31) << 2;  // B: row 0..7 (+8), col 0..124

  for (int k0 = 0; k0 < K; k0 += 16) {
#pragma unroll
    for (int i = 0; i < 2; ++i) {
      const float4 va = *reinterpret_cast<const float4*>(
          A + (size_t)(m0 + ar + 64 * i) * K + k0 + ac);
      As[ac + 0][ar + 64 * i] = va.x;
      As[ac + 1][ar + 64 * i] = va.y;
      As[ac + 2][ar + 64 * i] = va.z;
      As[ac + 3][ar + 64 * i] = va.w;
      const float4 vb = *reinterpret_cast<const float4*>(
          Bm + (size_t)(k0 + br + 8 * i) * N + n0 + bc);
      *reinterpret_cast<float4*>(&Bs[br + 8 * i][bc]) = vb;
    }
    __syncthreads();
#pragma unroll
    for (int kk = 0; kk < 16; ++kk) {
      float a[8], bv[8];
      *reinterpret_cast<float4*>(a) = *reinterpret_cast<const float4*>(&As[kk][ty * 8]);
      *reinterpret_cast<float4*>(a + 4) = *reinterpret_cast<const float4*>(&As[kk][ty * 8 + 4]);
      *reinterpret_cast<float4*>(bv) = *reinterpret_cast<const float4*>(&Bs[kk][tx * 8]);
      *reinterpret_cast<float4*>(bv + 4) = *reinterpret_cast<const float4*>(&Bs[kk][tx * 8 + 4]);
#pragma unroll
      for (int i = 0; i < 8; ++i)
#pragma unroll
        for (int j = 0; j < 8; ++j)
          acc[i][j] = fmaf(a[i], bv[j], acc[i][j]);
    }
    __syncthreads();
  }

#pragma unroll
  for (int i = 0; i < 8; ++i) {
    const int m = m0 + ty * 8 + i;
    float* cp = C + (size_t)m * N + n0 + tx * 8;
    float4 v0 = make_float4(acc[i][0], acc[i][1], acc[i][2], acc[i][3]);
    float4 v1 = make_float4(acc[i][4], acc[i][5], acc[i][6], acc[i][7]);
    if (EPI) {
      const float* bp = bias + n0 + tx * 8;
      const float* rp = resid + (size_t)m * N + n0 + tx * 8;
      v0.x += bp[0] + rp[0];
      v0.y += bp[1] + rp[1];
      v0.z += bp[2] + rp[2];
      v0.w += bp[3] + rp[3];
      v1.x += bp[4] + rp[4];
      v1.y += bp[5] + rp[5];
      v1.z += bp[6] + rp[6];
      v1.w += bp[7] + rp[7];
    }
    *reinterpret_cast<float4*>(cp) = v0;
    *reinterpret_cast<float4*>(cp + 4) = v1;
  }
}

// ---------------------------------------------------------------------------
// Stage 3: flash attention.  One block = (b, head, q-tile of 64 rows).
// qkv layout: [b][n][1536], q at col h*64, k at 512+h*64, v at 1024+h*64.
// out: [b][n][h*64+d]  (i.e. [16384][512])
// ---------------------------------------------------------------------------
__global__ __launch_bounds__(256) void attn_kernel(
    const float* __restrict__ qkv, float* __restrict__ out) {
  __shared__ float Qs[64][64];   // [d][q]  (transposed)
  __shared__ float KP[64][65];   // K as [d][k]; later reused as P [k][q]
  __shared__ float Vs[64][64];   // [k][d]

  const int t = threadIdx.x;
  const int qt = blockIdx.x & 15;
  const int h = (blockIdx.x >> 4) & 7;
  const int b = blockIdx.x >> 7;
  const size_t hbase = (size_t)b * NPIX * QKVW + (size_t)h * HD;
  const int tx = t & 15, ty = t >> 4;
  const int lr = t >> 4;            // load row 0..15
  const int lc = (t & 15) * 4;      // load col 0,4,...,60
  const int q0 = qt * 64;

  // Q tile (pre-scaled by d^-0.5 = 1/8), stored transposed [d][q]
#pragma unroll
  for (int i = 0; i < 4; ++i) {
    const int n = q0 + lr + 16 * i;
    const float4 v = *reinterpret_cast<const float4*>(qkv + hbase + (size_t)n * QKVW + lc);
    Qs[lc + 0][lr + 16 * i] = v.x * 0.125f;
    Qs[lc + 1][lr + 16 * i] = v.y * 0.125f;
    Qs[lc + 2][lr + 16 * i] = v.z * 0.125f;
    Qs[lc + 3][lr + 16 * i] = v.w * 0.125f;
  }

  float o[4][4] = {};
  float mrow[4] = {-1e30f, -1e30f, -1e30f, -1e30f};
  float lrow[4] = {0.f, 0.f, 0.f, 0.f};

  for (int kt = 0; kt < 16; ++kt) {
    __syncthreads();  // previous PV done (and Q load on first iter)
    const int n0 = kt * 64;
#pragma unroll
    for (int i = 0; i < 4; ++i) {
      const int n = n0 + lr + 16 * i;
      const float4 kv = *reinterpret_cast<const float4*>(
          qkv + hbase + 512 + (size_t)n * QKVW + lc);
      KP[lc + 0][lr + 16 * i] = kv.x;
      KP[lc + 1][lr + 16 * i] = kv.y;
      KP[lc + 2][lr + 16 * i] = kv.z;
      KP[lc + 3][lr + 16 * i] = kv.w;
      const float4 vv = *reinterpret_cast<const float4*>(
          qkv + hbase + 1024 + (size_t)n * QKVW + lc);
      *reinterpret_cast<float4*>(&Vs[lr + 16 * i][lc]) = vv;
    }
    __syncthreads();

    // S tile: s[i][j] = sum_d Q[q=ty*4+i][d] * K[k=tx*4+j][d]
    float s[4][4] = {};
    for (int d = 0; d < 64; ++d) {
      float qv[4], kv[4];
      *reinterpret_cast<float4*>(qv) = *reinterpret_cast<const float4*>(&Qs[d][ty * 4]);
      kv[0] = KP[d][tx * 4 + 0];
      kv[1] = KP[d][tx * 4 + 1];
      kv[2] = KP[d][tx * 4 + 2];
      kv[3] = KP[d][tx * 4 + 3];
#pragma unroll
      for (int i = 0; i < 4; ++i)
#pragma unroll
        for (int j = 0; j < 4; ++j)
          s[i][j] = fmaf(qv[i], kv[j], s[i][j]);
    }
    __syncthreads();  // everyone done reading K before overwriting with P

    // online softmax over the 16-lane tx-group (row = q)
#pragma unroll
    for (int i = 0; i < 4; ++i) {
      float mx = fmaxf(fmaxf(s[i][0], s[i][1]), fmaxf(s[i][2], s[i][3]));
#pragma unroll
      for (int m = 1; m < 16; m <<= 1) mx = fmaxf(mx, __shfl_xor(mx, m));
      const float mnew = fmaxf(mrow[i], mx);
      const float alpha = __expf(mrow[i] - mnew);
      mrow[i] = mnew;
      float rsum = 0.f;
#pragma unroll
      for (int j = 0; j < 4; ++j) {
        s[i][j] = __expf(s[i][j] - mnew);
        rsum += s[i][j];
      }
#pragma unroll
      for (int m = 1; m < 16; m <<= 1) rsum += __shfl_xor(rsum, m);
      lrow[i] = lrow[i] * alpha + rsum;
      o[i][0] *= alpha;
      o[i][1] *= alpha;
      o[i][2] *= alpha;
      o[i][3] *= alpha;
    }

    // write P (transposed: [k][q]) into KP
#pragma unroll
    for (int j = 0; j < 4; ++j)
#pragma unroll
      for (int i = 0; i < 4; ++i)
        KP[tx * 4 + j][ty * 4 + i] = s[i][j];
    __syncthreads();

    // PV: o[i][j] += sum_k P[q=ty*4+i][k] * V[k][d=tx*4+j]
    for (int kk = 0; kk < 64; ++kk) {
      float pv[4], vv[4];
      pv[0] = KP[kk][ty * 4 + 0];
      pv[1] = KP[kk][ty * 4 + 1];
      pv[2] = KP[kk][ty * 4 + 2];
      pv[3] = KP[kk][ty * 4 + 3];
      *reinterpret_cast<float4*>(vv) = *reinterpret_cast<const float4*>(&Vs[kk][tx * 4]);
#pragma unroll
      for (int i = 0; i < 4; ++i)
#pragma unroll
        for (int j = 0; j < 4; ++j)
          o[i][j] = fmaf(pv[i], vv[j], o[i][j]);
    }
  }

#pragma unroll
  for (int i = 0; i < 4; ++i) {
    const float inv = 1.f / lrow[i];
    const float4 v = make_float4(o[i][0] * inv, o[i][1] * inv, o[i][2] * inv, o[i][3] * inv);
    *reinterpret_cast<float4*>(
        out + (size_t)(b * NPIX + q0 + ty * 4 + i) * CH + h * HD + tx * 4) = v;
  }
}

// ---------------------------------------------------------------------------
extern "C" void kernel_launch(void* const* d_in, const int* in_sizes, int n_in,
                              void* d_out, int out_size, void* d_ws, size_t ws_size,
                              hipStream_t stream) {
  const float* x = (const float*)d_in[0];
  const float* gsc = (const float*)d_in[1];
  const float* gof = (const float*)d_in[2];
  const float* wqkv = (const float*)d_in[3];
  const float* wout = (const float*)d_in[4];
  const float* bout = (const float*)d_in[5];
  float* out = (float*)d_out;

  // workspace: qkv [16384][1536] fp32, then xbuf [16384][512] fp32
  // xbuf holds xn (gn+silu output) for stage 2, then attention output for stage 4.
  const size_t need = ((size_t)16384 * 1536 + (size_t)16384 * 512) * sizeof(float);
  if (ws_size < need) return;  // 128 MiB scratch required
  float* qkv = (float*)d_ws;
  float* xbuf = qkv + (size_t)16384 * 1536;

  gn_silu_kernel<<<BATCH * GROUPS, 256, 0, stream>>>(x, gsc, gof, xbuf);
  gemm128_kernel<false><<<(16384 / 128) * (1536 / 128), 256, 0, stream>>>(
      xbuf, wqkv, qkv, 16384, 1536, 512, nullptr, nullptr);
  attn_kernel<<<BATCH * HEADS * 16, 256, 0, stream>>>(qkv, xbuf);
  gemm128_kernel<true><<<(16384 / 128) * (512 / 128), 256, 0, stream>>>(
      xbuf, wout, out, 16384, 512, 512, bout, x);
}

// Round 2
// 347.772 us; speedup vs baseline: 2.7961x; 2.7961x over previous
//
#include <hip/hip_runtime.h>

#define BATCH 16
#define NPIX 1024      // 32*32
#define CH 512
#define HEADS 8
#define HD 64
#define GROUPS 32
#define CG 16          // CH/GROUPS
#define QKVW 1536      // 3*512

using bf16x8 = __attribute__((ext_vector_type(8))) short;  // 8 bf16 in 4 VGPRs
using f32x4  = __attribute__((ext_vector_type(4))) float;

__device__ inline unsigned short f2bf(float f) {
  unsigned int u = __builtin_bit_cast(unsigned int, f);
  u += 0x7fffu + ((u >> 16) & 1u);   // round-to-nearest-even
  return (unsigned short)(u >> 16);
}

// Swizzled LDS tile: rows of 64 bf16 (128 B = 8 16-byte slots), slot ^= row&7.
// Conflict-free for wave b128 reads of a 16-row x 16B column block (T2 recipe).
__device__ inline bf16x8 lds_frag(const unsigned short* S, int row, int slot) {
  return *(const bf16x8*)(S + row * 64 + (((slot ^ (row & 7)) << 3)));
}

// ---------------------------------------------------------------------------
// Weight transpose + bf16 convert: src fp32 [K][N] -> dst bf16 [N][K]
// 64x64 tiles, 256 threads.
// ---------------------------------------------------------------------------
__global__ __launch_bounds__(256) void wconv_kernel(
    const float* __restrict__ src, unsigned short* __restrict__ dst,
    const int K, const int N) {
  __shared__ float tile[64][65];
  const int nb = N >> 6;
  const int k0 = (blockIdx.x / nb) << 6, n0 = (blockIdx.x % nb) << 6;
  const int t = threadIdx.x;
  const int row = t >> 2, c0 = (t & 3) << 4;
#pragma unroll
  for (int j = 0; j < 4; ++j) {
    const float4 v = *reinterpret_cast<const float4*>(
        src + (size_t)(k0 + row) * N + n0 + c0 + j * 4);
    tile[row][c0 + j * 4 + 0] = v.x;
    tile[row][c0 + j * 4 + 1] = v.y;
    tile[row][c0 + j * 4 + 2] = v.z;
    tile[row][c0 + j * 4 + 3] = v.w;
  }
  __syncthreads();
  const int n = t >> 2, kc = (t & 3) << 4;
#pragma unroll
  for (int j = 0; j < 4; ++j) {
    ushort4 o;
    o.x = f2bf(tile[kc + j * 4 + 0][n]);
    o.y = f2bf(tile[kc + j * 4 + 1][n]);
    o.z = f2bf(tile[kc + j * 4 + 2][n]);
    o.w = f2bf(tile[kc + j * 4 + 3][n]);
    *reinterpret_cast<ushort4*>(dst + (size_t)(n0 + n) * K + k0 + kc + j * 4) = o;
  }
}

// ---------------------------------------------------------------------------
// Stage 1: GroupNorm + SiLU -> bf16.  One block = (b, g).
// ---------------------------------------------------------------------------
__global__ __launch_bounds__(256) void gn_silu_kernel(
    const float* __restrict__ x, const float* __restrict__ sc,
    const float* __restrict__ of, unsigned short* __restrict__ y) {
  const int b = blockIdx.x >> 5, g = blockIdx.x & 31;
  const size_t base = (size_t)b * NPIX * CH + (size_t)g * CG;
  const int t = threadIdx.x;

  float sum = 0.f, ssq = 0.f;
#pragma unroll
  for (int it = 0; it < 16; ++it) {
    const int e4 = t + 256 * it;
    const int p = e4 >> 2, c = (e4 & 3) * 4;
    const float4 v = *reinterpret_cast<const float4*>(x + base + (size_t)p * CH + c);
    sum += v.x + v.y + v.z + v.w;
    ssq += v.x * v.x + v.y * v.y + v.z * v.z + v.w * v.w;
  }
#pragma unroll
  for (int m = 32; m > 0; m >>= 1) {
    sum += __shfl_down(sum, m);
    ssq += __shfl_down(ssq, m);
  }
  __shared__ float rs[4], rq[4], mv[2];
  const int lane = t & 63, wid = t >> 6;
  if (lane == 0) { rs[wid] = sum; rq[wid] = ssq; }
  __syncthreads();
  if (t == 0) {
    const float s = rs[0] + rs[1] + rs[2] + rs[3];
    const float q = rq[0] + rq[1] + rq[2] + rq[3];
    const float mean = s * (1.f / 16384.f);
    const float var = q * (1.f / 16384.f) - mean * mean;
    mv[0] = mean;
    mv[1] = rsqrtf(var + 1e-5f);
  }
  __syncthreads();
  const float mean = mv[0], rstd = mv[1];

#pragma unroll
  for (int it = 0; it < 16; ++it) {
    const int e4 = t + 256 * it;
    const int p = e4 >> 2, c = (e4 & 3) * 4;
    const float4 v = *reinterpret_cast<const float4*>(x + base + (size_t)p * CH + c);
    const float4 s4 = *reinterpret_cast<const float4*>(sc + g * CG + c);
    const float4 o4 = *reinterpret_cast<const float4*>(of + g * CG + c);
    float r[4];
    r[0] = (v.x - mean) * rstd * s4.x + o4.x;
    r[1] = (v.y - mean) * rstd * s4.y + o4.y;
    r[2] = (v.z - mean) * rstd * s4.z + o4.z;
    r[3] = (v.w - mean) * rstd * s4.w + o4.w;
    ushort4 o;
    o.x = f2bf(r[0] / (1.f + __expf(-r[0])));
    o.y = f2bf(r[1] / (1.f + __expf(-r[1])));
    o.z = f2bf(r[2] / (1.f + __expf(-r[2])));
    o.w = f2bf(r[3] / (1.f + __expf(-r[3])));
    *reinterpret_cast<ushort4*>(y + base + (size_t)p * CH + c) = o;
  }
}

// ---------------------------------------------------------------------------
// bf16 MFMA GEMM: C[M,N] = A[M,K] @ B[K,N], B given transposed (BT [N][K]).
// 128x128 tile, BK=64, 256 threads (4 waves, each 64x64 -> 4x4 16x16 frags).
// K must be 512 (8 K-steps).  !EPI: C bf16.  EPI: C fp32 + bias + resid.
// ---------------------------------------------------------------------------
template <bool EPI>
__global__ __launch_bounds__(256) void gemm_bf16_kernel(
    const unsigned short* __restrict__ A, const unsigned short* __restrict__ BT,
    void* __restrict__ Cv, const int M, const int N,
    const float* __restrict__ bias, const float* __restrict__ resid) {
  __shared__ unsigned short As[128 * 64];
  __shared__ unsigned short Bs[128 * 64];
  const int Kd = 512;
  const int t = threadIdx.x;
  int bid = blockIdx.x;
  { const int q = gridDim.x >> 3; bid = (bid & 7) * q + (bid >> 3); }  // XCD swizzle
  const int nb = N >> 7;
  const int m0 = (bid / nb) << 7, n0 = (bid % nb) << 7;
  const int wv = t >> 6, lane = t & 63;
  const int wr = (wv >> 1) << 6, wc = (wv & 1) << 6;
  const int l15 = lane & 15, l4 = lane >> 4;

  const int srow = t >> 3, sslot = t & 7;   // staging: 32 rows/pass, 16B slots
  const unsigned short* ag = A + (size_t)(m0 + srow) * Kd + sslot * 8;
  const unsigned short* bg = BT + (size_t)(n0 + srow) * Kd + sslot * 8;
  const int wslot = (sslot ^ (srow & 7)) << 3;  // (srow+32i)&7 == srow&7

  f32x4 acc[4][4];
#pragma unroll
  for (int i = 0; i < 4; ++i)
#pragma unroll
    for (int j = 0; j < 4; ++j) acc[i][j] = {0.f, 0.f, 0.f, 0.f};

  uint4 ra[4], rb[4], ra2[4], rb2[4];
#pragma unroll
  for (int i = 0; i < 4; ++i) {
    ra[i] = *reinterpret_cast<const uint4*>(ag + (size_t)(32 * i) * Kd);
    rb[i] = *reinterpret_cast<const uint4*>(bg + (size_t)(32 * i) * Kd);
  }

#pragma unroll
  for (int s = 0; s < 8; ++s) {
    __syncthreads();
#pragma unroll
    for (int i = 0; i < 4; ++i) {
      *reinterpret_cast<uint4*>(As + (srow + 32 * i) * 64 + wslot) = ra[i];
      *reinterpret_cast<uint4*>(Bs + (srow + 32 * i) * 64 + wslot) = rb[i];
    }
    __syncthreads();
    if (s < 7) {
      const int k0 = (s + 1) * 64;
#pragma unroll
      for (int i = 0; i < 4; ++i) {
        ra2[i] = *reinterpret_cast<const uint4*>(ag + (size_t)(32 * i) * Kd + k0);
        rb2[i] = *reinterpret_cast<const uint4*>(bg + (size_t)(32 * i) * Kd + k0);
      }
    }
#pragma unroll
    for (int kk = 0; kk < 2; ++kk) {
      bf16x8 af[4], bf[4];
#pragma unroll
      for (int i = 0; i < 4; ++i) {
        af[i] = lds_frag(As, wr + i * 16 + l15, kk * 4 + l4);
        bf[i] = lds_frag(Bs, wc + i * 16 + l15, kk * 4 + l4);
      }
#pragma unroll
      for (int mi = 0; mi < 4; ++mi)
#pragma unroll
        for (int ni = 0; ni < 4; ++ni)
          acc[mi][ni] = __builtin_amdgcn_mfma_f32_16x16x32_bf16(
              af[mi], bf[ni], acc[mi][ni], 0, 0, 0);
    }
    if (s < 7) {
#pragma unroll
      for (int i = 0; i < 4; ++i) { ra[i] = ra2[i]; rb[i] = rb2[i]; }
    }
  }

  // epilogue: D row = (lane>>4)*4 + reg, col = lane&15  [m89-verified layout]
#pragma unroll
  for (int mi = 0; mi < 4; ++mi)
#pragma unroll
    for (int ni = 0; ni < 4; ++ni) {
      const int col = n0 + wc + ni * 16 + l15;
#pragma unroll
      for (int r = 0; r < 4; ++r) {
        const int row = m0 + wr + mi * 16 + l4 * 4 + r;
        const size_t idx = (size_t)row * N + col;
        if (EPI) {
          ((float*)Cv)[idx] = acc[mi][ni][r] + bias[col] + resid[idx];
        } else {
          ((unsigned short*)Cv)[idx] = f2bf(acc[mi][ni][r]);
        }
      }
    }
}

// ---------------------------------------------------------------------------
// Stage 3: flash attention, bf16 MFMA.  One block = (b, h, 128-q-row tile).
// 4 waves x 32 q-rows.  K-tiles of 64 keys.  Q in regs; K, V^T, P in LDS.
// qkv bf16 [16384][1536]; out bf16 [16384][512].
// ---------------------------------------------------------------------------
__global__ __launch_bounds__(256) void attn_mfma_kernel(
    const unsigned short* __restrict__ qkv, unsigned short* __restrict__ outb) {
  __shared__ unsigned short Ks[64 * 64];   // [key][d]  swizzled
  __shared__ unsigned short Vt[64 * 64];   // [d][key]  swizzled
  __shared__ unsigned short Ps[128 * 64];  // [q][key]  swizzled

  int bid = blockIdx.x;
  { const int q = gridDim.x >> 3; bid = (bid & 7) * q + (bid >> 3); }  // XCD swizzle
  const int qt = bid & 7, h = (bid >> 3) & 7, b = bid >> 6;
  const int t = threadIdx.x, wv = t >> 6, lane = t & 63;
  const int l15 = lane & 15, l4 = lane >> 4;
  const int q0 = qt * 128;
  const size_t base = (size_t)b * NPIX * QKVW + h * HD;

  // Q fragments (A-operand): row = l&15 within 16-row frag, k = (l>>4)*8..+7
  bf16x8 qf[2][2];
#pragma unroll
  for (int mi = 0; mi < 2; ++mi)
#pragma unroll
    for (int kk = 0; kk < 2; ++kk) {
      const int row = q0 + wv * 32 + mi * 16 + l15;
      qf[mi][kk] = *reinterpret_cast<const bf16x8*>(
          qkv + base + (size_t)row * QKVW + kk * 32 + l4 * 8);
    }

  f32x4 oacc[2][4];
#pragma unroll
  for (int i = 0; i < 2; ++i)
#pragma unroll
    for (int j = 0; j < 4; ++j) oacc[i][j] = {0.f, 0.f, 0.f, 0.f};
  float mrun[2][4], lrun[2][4];
#pragma unroll
  for (int i = 0; i < 2; ++i)
#pragma unroll
    for (int r = 0; r < 4; ++r) { mrun[i][r] = -3.0e38f; lrun[i][r] = 0.f; }

  const int srow = t >> 3, sslot = t & 7;

  for (int kt = 0; kt < 16; ++kt) {
    const int n0k = kt * 64;
    __syncthreads();  // prior PV reads of Ks/Vt done
#pragma unroll
    for (int i = 0; i < 2; ++i) {
      const int key = srow + 32 * i;
      const uint4 kv = *reinterpret_cast<const uint4*>(
          qkv + base + 512 + (size_t)(n0k + key) * QKVW + sslot * 8);
      *reinterpret_cast<uint4*>(Ks + key * 64 + ((sslot ^ (key & 7)) << 3)) = kv;
      const uint4 vv = *reinterpret_cast<const uint4*>(
          qkv + base + 1024 + (size_t)(n0k + key) * QKVW + sslot * 8);
      const unsigned short* vu = reinterpret_cast<const unsigned short*>(&vv);
#pragma unroll
      for (int j = 0; j < 8; ++j) {
        const int d = sslot * 8 + j;
        Vt[d * 64 + (key ^ ((d & 7) << 3))] = vu[j];  // transposed scalar write
      }
    }
    __syncthreads();

    // S = Q @ K^T   (B-operand: B[k=d][col=key] = Ks[key][d], k-contiguous)
    f32x4 sacc[2][4];
#pragma unroll
    for (int i = 0; i < 2; ++i)
#pragma unroll
      for (int j = 0; j < 4; ++j) sacc[i][j] = {0.f, 0.f, 0.f, 0.f};
#pragma unroll
    for (int kk = 0; kk < 2; ++kk) {
      bf16x8 kf[4];
#pragma unroll
      for (int ni = 0; ni < 4; ++ni)
        kf[ni] = lds_frag(Ks, ni * 16 + l15, kk * 4 + l4);
#pragma unroll
      for (int mi = 0; mi < 2; ++mi)
#pragma unroll
        for (int ni = 0; ni < 4; ++ni)
          sacc[mi][ni] = __builtin_amdgcn_mfma_f32_16x16x32_bf16(
              qf[mi][kk], kf[ni], sacc[mi][ni], 0, 0, 0);
    }

    // online softmax (rows live in the 16-lane l15 group; 4 rows per l4 group)
#pragma unroll
    for (int mi = 0; mi < 2; ++mi) {
#pragma unroll
      for (int r = 0; r < 4; ++r) {
        float v[4];
#pragma unroll
        for (int ni = 0; ni < 4; ++ni) v[ni] = sacc[mi][ni][r] * 0.125f;
        float mx = fmaxf(fmaxf(v[0], v[1]), fmaxf(v[2], v[3]));
#pragma unroll
        for (int m = 1; m < 16; m <<= 1) mx = fmaxf(mx, __shfl_xor(mx, m));
        const float mnew = fmaxf(mrun[mi][r], mx);
        const float alpha = __expf(mrun[mi][r] - mnew);
        mrun[mi][r] = mnew;
        float rsum = 0.f;
        unsigned short pb[4];
#pragma unroll
        for (int ni = 0; ni < 4; ++ni) {
          const float p = __expf(v[ni] - mnew);
          rsum += p;
          pb[ni] = f2bf(p);
        }
#pragma unroll
        for (int m = 1; m < 16; m <<= 1) rsum += __shfl_xor(rsum, m);
        lrun[mi][r] = lrun[mi][r] * alpha + rsum;
#pragma unroll
        for (int dn = 0; dn < 4; ++dn) {
          oacc[mi][dn][r] *= alpha;
        }
        const int prow = wv * 32 + mi * 16 + l4 * 4 + r;
#pragma unroll
        for (int ni = 0; ni < 4; ++ni)
          Ps[prow * 64 + ((ni * 16 + l15) ^ ((prow & 7) << 3))] = pb[ni];
      }
    }

    // own-wave LDS write->read ordering (each wave reads only its own P rows)
    asm volatile("s_waitcnt lgkmcnt(0)" ::: "memory");
    __builtin_amdgcn_sched_barrier(0);

    // O += P @ V   (A = Ps rows, B[k=key][col=d] = Vt[d][key], k-contiguous)
#pragma unroll
    for (int kk = 0; kk < 2; ++kk) {
      bf16x8 pf[2], vf[4];
#pragma unroll
      for (int mi = 0; mi < 2; ++mi)
        pf[mi] = lds_frag(Ps, wv * 32 + mi * 16 + l15, kk * 4 + l4);
#pragma unroll
      for (int dn = 0; dn < 4; ++dn)
        vf[dn] = lds_frag(Vt, dn * 16 + l15, kk * 4 + l4);
#pragma unroll
      for (int mi = 0; mi < 2; ++mi)
#pragma unroll
        for (int dn = 0; dn < 4; ++dn)
          oacc[mi][dn] = __builtin_amdgcn_mfma_f32_16x16x32_bf16(
              pf[mi], vf[dn], oacc[mi][dn], 0, 0, 0);
    }
  }

#pragma unroll
  for (int mi = 0; mi < 2; ++mi)
#pragma unroll
    for (int r = 0; r < 4; ++r) {
      const float inv = 1.f / lrun[mi][r];
      const int row = b * NPIX + q0 + wv * 32 + mi * 16 + l4 * 4 + r;
#pragma unroll
      for (int dn = 0; dn < 4; ++dn)
        outb[(size_t)row * CH + h * HD + dn * 16 + l15] =
            f2bf(oacc[mi][dn][r] * inv);
    }
}

// ---------------------------------------------------------------------------
extern "C" void kernel_launch(void* const* d_in, const int* in_sizes, int n_in,
                              void* d_out, int out_size, void* d_ws, size_t ws_size,
                              hipStream_t stream) {
  const float* x = (const float*)d_in[0];
  const float* gsc = (const float*)d_in[1];
  const float* gof = (const float*)d_in[2];
  const float* wqkv = (const float*)d_in[3];
  const float* wout = (const float*)d_in[4];
  const float* bout = (const float*)d_in[5];
  float* out = (float*)d_out;

  // ws: qkv bf16 [16384][1536] | xn/attn bf16 [16384][512] | wqT bf16 [1536][512]
  //     | woT bf16 [512][512]
  unsigned short* qkvb = (unsigned short*)d_ws;
  unsigned short* xnb = qkvb + (size_t)16384 * 1536;
  unsigned short* wqT = xnb + (size_t)16384 * 512;
  unsigned short* woT = wqT + (size_t)1536 * 512;
  const size_t need = ((size_t)16384 * 1536 + (size_t)16384 * 512 +
                       (size_t)1536 * 512 + (size_t)512 * 512) * 2;
  if (ws_size < need) return;

  wconv_kernel<<<(512 / 64) * (1536 / 64), 256, 0, stream>>>(wqkv, wqT, 512, 1536);
  wconv_kernel<<<(512 / 64) * (512 / 64), 256, 0, stream>>>(wout, woT, 512, 512);
  gn_silu_kernel<<<BATCH * GROUPS, 256, 0, stream>>>(x, gsc, gof, xnb);
  gemm_bf16_kernel<false><<<(16384 / 128) * (1536 / 128), 256, 0, stream>>>(
      xnb, wqT, qkvb, 16384, 1536, nullptr, nullptr);
  attn_mfma_kernel<<<BATCH * HEADS * 8, 256, 0, stream>>>(qkvb, xnb);
  gemm_bf16_kernel<true><<<(16384 / 128) * (512 / 128), 256, 0, stream>>>(
      xnb, woT, out, 16384, 512, bout, x);
}

// Round 3
// 339.846 us; speedup vs baseline: 2.8613x; 1.0233x over previous
//
#include <hip/hip_runtime.h>

#define BATCH 16
#define NPIX 1024      // 32*32
#define CH 512
#define HEADS 8
#define HD 64
#define GROUPS 32
#define CG 16          // CH/GROUPS
#define QKVW 1536      // 3*512

using bf16x8 = __attribute__((ext_vector_type(8))) short;  // 8 bf16 in 4 VGPRs
using f32x4  = __attribute__((ext_vector_type(4))) float;

__device__ inline unsigned short f2bf(float f) {
  unsigned int u = __builtin_bit_cast(unsigned int, f);
  u += 0x7fffu + ((u >> 16) & 1u);   // round-to-nearest-even
  return (unsigned short)(u >> 16);
}

// Swizzled LDS tile: rows of 64 bf16 (128 B = 8 16-byte slots), slot ^= row&7.
__device__ inline bf16x8 lds_frag(const unsigned short* S, int row, int slot) {
  return *(const bf16x8*)(S + row * 64 + (((slot ^ (row & 7)) << 3)));
}

// ---------------------------------------------------------------------------
// Weight transpose + bf16 convert: src fp32 [K][N] -> dst bf16 [N][K]
// ---------------------------------------------------------------------------
__global__ __launch_bounds__(256) void wconv_kernel(
    const float* __restrict__ src, unsigned short* __restrict__ dst,
    const int K, const int N) {
  __shared__ float tile[64][65];
  const int nb = N >> 6;
  const int k0 = (blockIdx.x / nb) << 6, n0 = (blockIdx.x % nb) << 6;
  const int t = threadIdx.x;
  const int row = t >> 2, c0 = (t & 3) << 4;
#pragma unroll
  for (int j = 0; j < 4; ++j) {
    const float4 v = *reinterpret_cast<const float4*>(
        src + (size_t)(k0 + row) * N + n0 + c0 + j * 4);
    tile[row][c0 + j * 4 + 0] = v.x;
    tile[row][c0 + j * 4 + 1] = v.y;
    tile[row][c0 + j * 4 + 2] = v.z;
    tile[row][c0 + j * 4 + 3] = v.w;
  }
  __syncthreads();
  const int n = t >> 2, kc = (t & 3) << 4;
#pragma unroll
  for (int j = 0; j < 4; ++j) {
    ushort4 o;
    o.x = f2bf(tile[kc + j * 4 + 0][n]);
    o.y = f2bf(tile[kc + j * 4 + 1][n]);
    o.z = f2bf(tile[kc + j * 4 + 2][n]);
    o.w = f2bf(tile[kc + j * 4 + 3][n]);
    *reinterpret_cast<ushort4*>(dst + (size_t)(n0 + n) * K + k0 + kc + j * 4) = o;
  }
}

// ---------------------------------------------------------------------------
// Stage 1: GroupNorm + SiLU -> bf16.  One block = (b, g).  x cached in regs.
// ---------------------------------------------------------------------------
__global__ __launch_bounds__(256) void gn_silu_kernel(
    const float* __restrict__ x, const float* __restrict__ sc,
    const float* __restrict__ of, unsigned short* __restrict__ y) {
  const int b = blockIdx.x >> 5, g = blockIdx.x & 31;
  const size_t base = (size_t)b * NPIX * CH + (size_t)g * CG;
  const int t = threadIdx.x;

  float4 vv[16];
  float sum = 0.f, ssq = 0.f;
#pragma unroll
  for (int it = 0; it < 16; ++it) {
    const int e4 = t + 256 * it;
    const int p = e4 >> 2, c = (e4 & 3) * 4;
    vv[it] = *reinterpret_cast<const float4*>(x + base + (size_t)p * CH + c);
    sum += vv[it].x + vv[it].y + vv[it].z + vv[it].w;
    ssq += vv[it].x * vv[it].x + vv[it].y * vv[it].y +
           vv[it].z * vv[it].z + vv[it].w * vv[it].w;
  }
#pragma unroll
  for (int m = 32; m > 0; m >>= 1) {
    sum += __shfl_down(sum, m);
    ssq += __shfl_down(ssq, m);
  }
  __shared__ float rs[4], rq[4], mv[2];
  const int lane = t & 63, wid = t >> 6;
  if (lane == 0) { rs[wid] = sum; rq[wid] = ssq; }
  __syncthreads();
  if (t == 0) {
    const float s = rs[0] + rs[1] + rs[2] + rs[3];
    const float q = rq[0] + rq[1] + rq[2] + rq[3];
    const float mean = s * (1.f / 16384.f);
    const float var = q * (1.f / 16384.f) - mean * mean;
    mv[0] = mean;
    mv[1] = rsqrtf(var + 1e-5f);
  }
  __syncthreads();
  const float mean = mv[0], rstd = mv[1];

#pragma unroll
  for (int it = 0; it < 16; ++it) {
    const int e4 = t + 256 * it;
    const int p = e4 >> 2, c = (e4 & 3) * 4;
    const float4 s4 = *reinterpret_cast<const float4*>(sc + g * CG + c);
    const float4 o4 = *reinterpret_cast<const float4*>(of + g * CG + c);
    float r[4];
    r[0] = (vv[it].x - mean) * rstd * s4.x + o4.x;
    r[1] = (vv[it].y - mean) * rstd * s4.y + o4.y;
    r[2] = (vv[it].z - mean) * rstd * s4.z + o4.z;
    r[3] = (vv[it].w - mean) * rstd * s4.w + o4.w;
    ushort4 o;
    o.x = f2bf(r[0] / (1.f + __expf(-r[0])));
    o.y = f2bf(r[1] / (1.f + __expf(-r[1])));
    o.z = f2bf(r[2] / (1.f + __expf(-r[2])));
    o.w = f2bf(r[3] / (1.f + __expf(-r[3])));
    *reinterpret_cast<ushort4*>(y + base + (size_t)p * CH + c) = o;
  }
}

// ---------------------------------------------------------------------------
// bf16 MFMA GEMM: C[M,N] = A[M,K] @ B[K,N], B given transposed (BT [N][K]).
// 128x128 tile, BK=64, 4 waves.  K fixed 512.
// !EPI, n0<1024 : C bf16 row-major (Q,K thirds of qkv)
// !EPI, n0>=1024: swapped-operand MFMA -> writes V^T into vT[b*512+vcol][1024]
// EPI           : C fp32 + bias + resid
// ---------------------------------------------------------------------------
template <bool EPI>
__global__ __launch_bounds__(256) void gemm_bf16_kernel(
    const unsigned short* __restrict__ A, const unsigned short* __restrict__ BT,
    void* __restrict__ Cv, const int M, const int N,
    const float* __restrict__ bias, const float* __restrict__ resid,
    unsigned short* __restrict__ vT) {
  __shared__ unsigned short As[128 * 64];
  __shared__ unsigned short Bs[128 * 64];
  const int Kd = 512;
  const int t = threadIdx.x;
  int bid = blockIdx.x;
  { const int q = gridDim.x >> 3; bid = (bid & 7) * q + (bid >> 3); }  // XCD swizzle
  const int nb = N >> 7;
  const int m0 = (bid / nb) << 7, n0 = (bid % nb) << 7;
  const int wv = t >> 6, lane = t & 63;
  const int wr = (wv >> 1) << 6, wc = (wv & 1) << 6;
  const int l15 = lane & 15, l4 = lane >> 4;
  const bool vmode = !EPI && (n0 >= 1024);

  const int srow = t >> 3, sslot = t & 7;
  const unsigned short* ag = A + (size_t)(m0 + srow) * Kd + sslot * 8;
  const unsigned short* bg = BT + (size_t)(n0 + srow) * Kd + sslot * 8;
  const int wslot = (sslot ^ (srow & 7)) << 3;

  f32x4 acc[4][4];
#pragma unroll
  for (int i = 0; i < 4; ++i)
#pragma unroll
    for (int j = 0; j < 4; ++j) acc[i][j] = {0.f, 0.f, 0.f, 0.f};

  uint4 ra[4], rb[4], ra2[4], rb2[4];
#pragma unroll
  for (int i = 0; i < 4; ++i) {
    ra[i] = *reinterpret_cast<const uint4*>(ag + (size_t)(32 * i) * Kd);
    rb[i] = *reinterpret_cast<const uint4*>(bg + (size_t)(32 * i) * Kd);
  }

#pragma unroll
  for (int s = 0; s < 8; ++s) {
    __syncthreads();
#pragma unroll
    for (int i = 0; i < 4; ++i) {
      *reinterpret_cast<uint4*>(As + (srow + 32 * i) * 64 + wslot) = ra[i];
      *reinterpret_cast<uint4*>(Bs + (srow + 32 * i) * 64 + wslot) = rb[i];
    }
    __syncthreads();
    if (s < 7) {
      const int k0 = (s + 1) * 64;
#pragma unroll
      for (int i = 0; i < 4; ++i) {
        ra2[i] = *reinterpret_cast<const uint4*>(ag + (size_t)(32 * i) * Kd + k0);
        rb2[i] = *reinterpret_cast<const uint4*>(bg + (size_t)(32 * i) * Kd + k0);
      }
    }
#pragma unroll
    for (int kk = 0; kk < 2; ++kk) {
      bf16x8 af[4], bf[4];
#pragma unroll
      for (int i = 0; i < 4; ++i) {
        af[i] = lds_frag(As, wr + i * 16 + l15, kk * 4 + l4);
        bf[i] = lds_frag(Bs, wc + i * 16 + l15, kk * 4 + l4);
      }
      if (vmode) {
#pragma unroll
        for (int ni = 0; ni < 4; ++ni)
#pragma unroll
          for (int mi = 0; mi < 4; ++mi)
            acc[ni][mi] = __builtin_amdgcn_mfma_f32_16x16x32_bf16(
                bf[ni], af[mi], acc[ni][mi], 0, 0, 0);
      } else {
#pragma unroll
        for (int mi = 0; mi < 4; ++mi)
#pragma unroll
          for (int ni = 0; ni < 4; ++ni)
            acc[mi][ni] = __builtin_amdgcn_mfma_f32_16x16x32_bf16(
                af[mi], bf[ni], acc[mi][ni], 0, 0, 0);
      }
    }
    if (s < 7) {
#pragma unroll
      for (int i = 0; i < 4; ++i) { ra[i] = ra2[i]; rb[i] = rb2[i]; }
    }
  }

  if (vmode) {
    // acc[ni][mi] = V^T frag: row = v-col (n0-1024+wc+ni*16+l4*4+r),
    // col = token row (m0+wr+mi*16+l15).  vT[(b*512 + vcol)][pix]
    const int bb = m0 >> 10;
    const int pbase = (m0 & 1023) + wr;
#pragma unroll
    for (int ni = 0; ni < 4; ++ni)
#pragma unroll
      for (int mi = 0; mi < 4; ++mi) {
        const int p = pbase + mi * 16 + l15;
#pragma unroll
        for (int r = 0; r < 4; ++r) {
          const int vcol = (n0 - 1024) + wc + ni * 16 + l4 * 4 + r;
          vT[(((size_t)(bb * 512 + vcol)) << 10) + p] = f2bf(acc[ni][mi][r]);
        }
      }
  } else {
#pragma unroll
    for (int mi = 0; mi < 4; ++mi)
#pragma unroll
      for (int ni = 0; ni < 4; ++ni) {
        const int col = n0 + wc + ni * 16 + l15;
#pragma unroll
        for (int r = 0; r < 4; ++r) {
          const int row = m0 + wr + mi * 16 + l4 * 4 + r;
          const size_t idx = (size_t)row * N + col;
          if (EPI) {
            ((float*)Cv)[idx] = acc[mi][ni][r] + bias[col] + resid[idx];
          } else {
            ((unsigned short*)Cv)[idx] = f2bf(acc[mi][ni][r]);
          }
        }
      }
  }
}

// ---------------------------------------------------------------------------
// Stage 3: flash attention, bf16 MFMA, swapped-operand layout.
// One block = (b, h, 128-q tile); 4 waves x 32 q.  K-tiles of 64 keys.
// S^T = mfma(K,Q) so q lives in lane&15 -> softmax = in-lane + 2 shuffles.
// O^T = mfma(V^T, P).  V^T pre-transposed in global (vT).
// ---------------------------------------------------------------------------
__global__ __launch_bounds__(256) void attn_mfma_kernel(
    const unsigned short* __restrict__ qkv, const unsigned short* __restrict__ vT,
    unsigned short* __restrict__ outb) {
  __shared__ unsigned short Ks[64 * 64];   // [key][d]  swizzled
  __shared__ unsigned short Vt[64 * 64];   // [d][key]  swizzled
  __shared__ unsigned short Ps[128 * 64];  // [q][key]  swizzled

  int bid = blockIdx.x;
  { const int q = gridDim.x >> 3; bid = (bid & 7) * q + (bid >> 3); }  // XCD swizzle
  const int qt = bid & 7, h = (bid >> 3) & 7, b = bid >> 6;
  const int t = threadIdx.x, wv = t >> 6, lane = t & 63;
  const int l15 = lane & 15, l4 = lane >> 4;
  const int q0 = qt * 128;
  const size_t base = (size_t)b * NPIX * QKVW + h * HD;

  // Q fragments (B-operand): col=q from l15, k = d contiguous
  bf16x8 qf[2][2];
#pragma unroll
  for (int mi = 0; mi < 2; ++mi)
#pragma unroll
    for (int kk = 0; kk < 2; ++kk) {
      const int row = q0 + wv * 32 + mi * 16 + l15;
      qf[mi][kk] = *reinterpret_cast<const bf16x8*>(
          qkv + base + (size_t)row * QKVW + kk * 32 + l4 * 8);
    }

  f32x4 oaccT[4][2];  // [dn][mi]: O^T[d][q]
#pragma unroll
  for (int i = 0; i < 4; ++i)
#pragma unroll
    for (int j = 0; j < 2; ++j) oaccT[i][j] = {0.f, 0.f, 0.f, 0.f};
  float mrun[2] = {-3.0e38f, -3.0e38f}, lrun[2] = {0.f, 0.f};

  const int srow = t >> 3, sslot = t & 7;
  const unsigned short* kgp = qkv + base + 512 + (size_t)srow * QKVW + sslot * 8;
  const unsigned short* vgp =
      vT + (((size_t)(b * 512 + h * HD + srow)) << 10) + sslot * 8;
  const int wso = (sslot ^ (srow & 7)) << 3;

  uint4 kr[2], vr[2];
#pragma unroll
  for (int i = 0; i < 2; ++i) {
    kr[i] = *reinterpret_cast<const uint4*>(kgp + (size_t)(32 * i) * QKVW);
    vr[i] = *reinterpret_cast<const uint4*>(vgp + ((size_t)(32 * i) << 10));
  }

  for (int kt = 0; kt < 16; ++kt) {
    __syncthreads();  // prior tile's frag reads done
#pragma unroll
    for (int i = 0; i < 2; ++i) {
      const int rrow = srow + 32 * i;
      *reinterpret_cast<uint4*>(Ks + rrow * 64 + wso) = kr[i];
      *reinterpret_cast<uint4*>(Vt + rrow * 64 + wso) = vr[i];
    }
    __syncthreads();
    if (kt < 15) {
      const int n0n = (kt + 1) * 64;
#pragma unroll
      for (int i = 0; i < 2; ++i) {
        kr[i] = *reinterpret_cast<const uint4*>(
            kgp + (size_t)(n0n + 32 * i) * QKVW);
        vr[i] = *reinterpret_cast<const uint4*>(
            vgp + ((size_t)(32 * i) << 10) + n0n);
      }
    }

    // S^T = K @ Q^T : sacc[ni][mi], row = key (l4*4+r), col = q (l15)
    f32x4 sacc[4][2];
#pragma unroll
    for (int i = 0; i < 4; ++i)
#pragma unroll
      for (int j = 0; j < 2; ++j) sacc[i][j] = {0.f, 0.f, 0.f, 0.f};
#pragma unroll
    for (int kk = 0; kk < 2; ++kk) {
      bf16x8 kf[4];
#pragma unroll
      for (int ni = 0; ni < 4; ++ni)
        kf[ni] = lds_frag(Ks, ni * 16 + l15, kk * 4 + l4);
#pragma unroll
      for (int ni = 0; ni < 4; ++ni)
#pragma unroll
        for (int mi = 0; mi < 2; ++mi)
          sacc[ni][mi] = __builtin_amdgcn_mfma_f32_16x16x32_bf16(
              kf[ni], qf[mi][kk], sacc[ni][mi], 0, 0, 0);
    }

    // online softmax: per lane, q = l15 (one per mi); 16 in-reg key values
#pragma unroll
    for (int mi = 0; mi < 2; ++mi) {
      float mx = sacc[0][mi][0];
#pragma unroll
      for (int ni = 0; ni < 4; ++ni)
#pragma unroll
        for (int r = 0; r < 4; ++r) mx = fmaxf(mx, sacc[ni][mi][r]);
      mx = fmaxf(mx, __shfl_xor(mx, 16));
      mx = fmaxf(mx, __shfl_xor(mx, 32));
      const float mnew = fmaxf(mrun[mi], mx * 0.125f);
      const float alpha = __expf(mrun[mi] - mnew);
      mrun[mi] = mnew;
      const int prow = wv * 32 + mi * 16 + l15;
      float rsum = 0.f;
#pragma unroll
      for (int ni = 0; ni < 4; ++ni) {
        float p[4];
#pragma unroll
        for (int r = 0; r < 4; ++r) {
          p[r] = __expf(sacc[ni][mi][r] * 0.125f - mnew);
          rsum += p[r];
        }
        ushort4 pw;
        pw.x = f2bf(p[0]); pw.y = f2bf(p[1]);
        pw.z = f2bf(p[2]); pw.w = f2bf(p[3]);
        const int slot = ni * 2 + (l4 >> 1);
        *reinterpret_cast<ushort4*>(
            Ps + prow * 64 + ((slot ^ (prow & 7)) << 3) + ((l4 & 1) << 2)) = pw;
      }
      rsum += __shfl_xor(rsum, 16);
      rsum += __shfl_xor(rsum, 32);
      lrun[mi] = lrun[mi] * alpha + rsum;
#pragma unroll
      for (int dn = 0; dn < 4; ++dn) {
#pragma unroll
        for (int r = 0; r < 4; ++r) oaccT[dn][mi][r] *= alpha;
      }
    }

    // own-wave P write->read ordering
    asm volatile("s_waitcnt lgkmcnt(0)" ::: "memory");
    __builtin_amdgcn_sched_barrier(0);

    // O^T += V^T @ P^T : A = Vt rows (d), B = Ps rows (q)
#pragma unroll
    for (int kk = 0; kk < 2; ++kk) {
      bf16x8 vf[4], pf[2];
#pragma unroll
      for (int dn = 0; dn < 4; ++dn)
        vf[dn] = lds_frag(Vt, dn * 16 + l15, kk * 4 + l4);
#pragma unroll
      for (int mi = 0; mi < 2; ++mi)
        pf[mi] = lds_frag(Ps, wv * 32 + mi * 16 + l15, kk * 4 + l4);
#pragma unroll
      for (int dn = 0; dn < 4; ++dn)
#pragma unroll
        for (int mi = 0; mi < 2; ++mi)
          oaccT[dn][mi] = __builtin_amdgcn_mfma_f32_16x16x32_bf16(
              vf[dn], pf[mi], oaccT[dn][mi], 0, 0, 0);
    }
  }

  // output: O^T[d][q] -> out[n(q)][h*64+d]; pack 4 d-consecutive per store
#pragma unroll
  for (int mi = 0; mi < 2; ++mi) {
    const float inv = 1.f / lrun[mi];
    const size_t n = (size_t)b * NPIX + q0 + wv * 32 + mi * 16 + l15;
#pragma unroll
    for (int dn = 0; dn < 4; ++dn) {
      ushort4 o;
      o.x = f2bf(oaccT[dn][mi][0] * inv);
      o.y = f2bf(oaccT[dn][mi][1] * inv);
      o.z = f2bf(oaccT[dn][mi][2] * inv);
      o.w = f2bf(oaccT[dn][mi][3] * inv);
      *reinterpret_cast<ushort4*>(outb + n * CH + h * HD + dn * 16 + l4 * 4) = o;
    }
  }
}

// ---------------------------------------------------------------------------
extern "C" void kernel_launch(void* const* d_in, const int* in_sizes, int n_in,
                              void* d_out, int out_size, void* d_ws, size_t ws_size,
                              hipStream_t stream) {
  const float* x = (const float*)d_in[0];
  const float* gsc = (const float*)d_in[1];
  const float* gof = (const float*)d_in[2];
  const float* wqkv = (const float*)d_in[3];
  const float* wout = (const float*)d_in[4];
  const float* bout = (const float*)d_in[5];
  float* out = (float*)d_out;

  unsigned short* qkvb = (unsigned short*)d_ws;                  // [16384][1536]
  unsigned short* xnb = qkvb + (size_t)16384 * 1536;             // [16384][512]
  unsigned short* wqT = xnb + (size_t)16384 * 512;               // [1536][512]
  unsigned short* woT = wqT + (size_t)1536 * 512;                // [512][512]
  unsigned short* vTb = woT + (size_t)512 * 512;                 // [16*512][1024]
  const size_t need = ((size_t)16384 * 1536 + (size_t)16384 * 512 +
                       (size_t)1536 * 512 + (size_t)512 * 512 +
                       (size_t)16 * 512 * 1024) * 2;
  if (ws_size < need) return;

  wconv_kernel<<<(512 / 64) * (1536 / 64), 256, 0, stream>>>(wqkv, wqT, 512, 1536);
  wconv_kernel<<<(512 / 64) * (512 / 64), 256, 0, stream>>>(wout, woT, 512, 512);
  gn_silu_kernel<<<BATCH * GROUPS, 256, 0, stream>>>(x, gsc, gof, xnb);
  gemm_bf16_kernel<false><<<(16384 / 128) * (1536 / 128), 256, 0, stream>>>(
      xnb, wqT, qkvb, 16384, 1536, nullptr, nullptr, vTb);
  attn_mfma_kernel<<<BATCH * HEADS * 8, 256, 0, stream>>>(qkvb, vTb, xnb);
  gemm_bf16_kernel<true><<<(16384 / 128) * (512 / 128), 256, 0, stream>>>(
      xnb, woT, out, 16384, 512, bout, x, nullptr);
}